// Round 5
// baseline (708.456 us; speedup 1.0000x reference)
//
#include <hip/hip_runtime.h>

#define RES 32
#define R3 (RES * RES * RES)

// ---------------------------------------------------------------------------
// K1a: partial coordinate sums, float4 loads. grid (16, B), block 256.
// ---------------------------------------------------------------------------
__global__ void sums_kernel(const float* __restrict__ coords,
                            float* __restrict__ accum, int N) {
    const int b = blockIdx.y;
    const int stride = gridDim.x * blockDim.x;
    const float* cb = coords + (size_t)b * 3 * N;
    const int nvec = N >> 2;
    const float4* c0 = (const float4*)cb;
    const float4* c1 = (const float4*)(cb + N);
    const float4* c2 = (const float4*)(cb + 2 * N);

    float s0 = 0.f, s1 = 0.f, s2 = 0.f;
    for (int n = blockIdx.x * blockDim.x + threadIdx.x; n < nvec; n += stride) {
        float4 a = c0[n]; s0 += (a.x + a.y) + (a.z + a.w);
        float4 c = c1[n]; s1 += (c.x + c.y) + (c.z + c.w);
        float4 d = c2[n]; s2 += (d.x + d.y) + (d.z + d.w);
    }
    if (blockIdx.x == 0 && threadIdx.x == 0) {
        for (int n = nvec << 2; n < N; ++n) {
            s0 += cb[n]; s1 += cb[N + n]; s2 += cb[2 * N + n];
        }
    }
    for (int off = 32; off; off >>= 1) {
        s0 += __shfl_down(s0, off);
        s1 += __shfl_down(s1, off);
        s2 += __shfl_down(s2, off);
    }
    __shared__ float r0[4], r1[4], r2[4];
    const int lane = threadIdx.x & 63, wv = threadIdx.x >> 6;
    if (lane == 0) { r0[wv] = s0; r1[wv] = s1; r2[wv] = s2; }
    __syncthreads();
    if (threadIdx.x == 0) {
        float t0 = 0.f, t1 = 0.f, t2 = 0.f;
        const int nw = blockDim.x >> 6;
        for (int w = 0; w < nw; ++w) { t0 += r0[w]; t1 += r1[w]; t2 += r2[w]; }
        unsafeAtomicAdd(&accum[b * 4 + 0], t0);
        unsafeAtomicAdd(&accum[b * 4 + 1], t1);
        unsafeAtomicAdd(&accum[b * 4 + 2], t2);
    }
}

// ---------------------------------------------------------------------------
// K1b: partial max squared centered norm, float4 loads. grid (16, B).
// ---------------------------------------------------------------------------
__global__ void maxn_kernel(const float* __restrict__ coords,
                            const float* __restrict__ accum,
                            unsigned* __restrict__ maxsq, int N) {
    const int b = blockIdx.y;
    const int stride = gridDim.x * blockDim.x;
    const float* cb = coords + (size_t)b * 3 * N;
    const float m0 = accum[b * 4 + 0] / (float)N;
    const float m1 = accum[b * 4 + 1] / (float)N;
    const float m2 = accum[b * 4 + 2] / (float)N;
    const int nvec = N >> 2;
    const float4* c0 = (const float4*)cb;
    const float4* c1 = (const float4*)(cb + N);
    const float4* c2 = (const float4*)(cb + 2 * N);

    float mx = 0.f;
    for (int n = blockIdx.x * blockDim.x + threadIdx.x; n < nvec; n += stride) {
        float4 a = c0[n], c = c1[n], d = c2[n];
        a.x -= m0; a.y -= m0; a.z -= m0; a.w -= m0;
        c.x -= m1; c.y -= m1; c.z -= m1; c.w -= m1;
        d.x -= m2; d.y -= m2; d.z -= m2; d.w -= m2;
        mx = fmaxf(mx, a.x * a.x + c.x * c.x + d.x * d.x);
        mx = fmaxf(mx, a.y * a.y + c.y * c.y + d.y * d.y);
        mx = fmaxf(mx, a.z * a.z + c.z * c.z + d.z * d.z);
        mx = fmaxf(mx, a.w * a.w + c.w * c.w + d.w * d.w);
    }
    if (blockIdx.x == 0 && threadIdx.x == 0) {
        for (int n = nvec << 2; n < N; ++n) {
            float a = cb[n] - m0, c = cb[N + n] - m1, d = cb[2 * N + n] - m2;
            mx = fmaxf(mx, a * a + c * c + d * d);
        }
    }
    for (int off = 32; off; off >>= 1) mx = fmaxf(mx, __shfl_down(mx, off));
    __shared__ float r0[4];
    const int lane = threadIdx.x & 63, wv = threadIdx.x >> 6;
    if (lane == 0) r0[wv] = mx;
    __syncthreads();
    if (threadIdx.x == 0) {
        const int nw = blockDim.x >> 6;
        for (int w = 0; w < nw; ++w) mx = fmaxf(mx, r0[w]);
        atomicMax(&maxsq[b], __float_as_uint(mx));  // int atomic: native
    }
}

// ---------------------------------------------------------------------------
// K2: per-point normalize + voxel index (u16) + counts. 4 points/thread.
// True division to keep voxel indices bit-identical to ref.
// ---------------------------------------------------------------------------
__global__ void point_kernel(const float* __restrict__ coords,
                             const float* __restrict__ accum,
                             const unsigned* __restrict__ maxsq,
                             float* __restrict__ nc_out,
                             unsigned short* __restrict__ idx_out,
                             int* __restrict__ counts, int N) {
    const int n4 = blockIdx.x * blockDim.x + threadIdx.x;
    const int b = blockIdx.y;
    const int nvec = (N + 3) >> 2;
    if (n4 >= nvec) return;

    const float* cb = coords + (size_t)b * 3 * N;
    const float m0 = accum[b * 4 + 0] / (float)N;
    const float m1 = accum[b * 4 + 1] / (float)N;
    const float m2 = accum[b * 4 + 2] / (float)N;
    const float denom = 2.0f * sqrtf(__uint_as_float(maxsq[b]));
    float* ncb = nc_out + (size_t)b * 3 * N;
    unsigned short* irow = idx_out + (size_t)b * N;
    int* crow = counts + (size_t)b * R3;

    const int n0 = n4 << 2;
    if (n0 + 3 < N) {
        float4 a = *(const float4*)(cb + n0);
        float4 c = *(const float4*)(cb + N + n0);
        float4 d = *(const float4*)(cb + 2 * N + n0);
        float4 v0, v1, v2;
        int4 id;
        #define PROC(comp)                                                        \
        {                                                                         \
            float x = (a.comp - m0) / denom + 0.5f;                               \
            float y = (c.comp - m1) / denom + 0.5f;                               \
            float z = (d.comp - m2) / denom + 0.5f;                               \
            v0.comp = fminf(fmaxf(x * (float)RES, 0.f), (float)(RES - 1));        \
            v1.comp = fminf(fmaxf(y * (float)RES, 0.f), (float)(RES - 1));        \
            v2.comp = fminf(fmaxf(z * (float)RES, 0.f), (float)(RES - 1));        \
            id.comp = (int)rintf(v0.comp) * RES * RES                             \
                    + (int)rintf(v1.comp) * RES + (int)rintf(v2.comp);            \
        }
        PROC(x) PROC(y) PROC(z) PROC(w)
        #undef PROC
        *(float4*)(ncb + n0) = v0;
        *(float4*)(ncb + N + n0) = v1;
        *(float4*)(ncb + 2 * N + n0) = v2;
        ushort4 us;
        us.x = (unsigned short)id.x; us.y = (unsigned short)id.y;
        us.z = (unsigned short)id.z; us.w = (unsigned short)id.w;
        *(ushort4*)(irow + n0) = us;
        atomicAdd(&crow[id.x], 1);
        atomicAdd(&crow[id.y], 1);
        atomicAdd(&crow[id.z], 1);
        atomicAdd(&crow[id.w], 1);
    } else {
        for (int n = n0; n < N; ++n) {
            float x = (cb[n] - m0) / denom + 0.5f;
            float y = (cb[N + n] - m1) / denom + 0.5f;
            float z = (cb[2 * N + n] - m2) / denom + 0.5f;
            float v0 = fminf(fmaxf(x * (float)RES, 0.f), (float)(RES - 1));
            float v1 = fminf(fmaxf(y * (float)RES, 0.f), (float)(RES - 1));
            float v2 = fminf(fmaxf(z * (float)RES, 0.f), (float)(RES - 1));
            ncb[n] = v0; ncb[N + n] = v1; ncb[2 * N + n] = v2;
            int id = (int)rintf(v0) * RES * RES + (int)rintf(v1) * RES + (int)rintf(v2);
            irow[n] = (unsigned short)id;
            atomicAdd(&crow[id], 1);
        }
    }
}

// ---------------------------------------------------------------------------
// K3: per-batch exclusive prefix scan of counts (R3=32768 = 1024 thr x 32).
// Writes start[] (u16) and cursor[] (i32, consumed by plist build).
// ---------------------------------------------------------------------------
__global__ __launch_bounds__(1024) void scan_kernel(
        const int* __restrict__ counts,
        int* __restrict__ cursor,
        unsigned short* __restrict__ start) {
    const int b = blockIdx.x;
    const int tid = threadIdx.x;
    const int lane = tid & 63, wv = tid >> 6;
    const int base = tid * 32;
    const int* crow = counts + (size_t)b * R3;

    int vals[32];
    int tot = 0;
    const int4* c4 = (const int4*)(crow + base);
    for (int i = 0; i < 8; ++i) {
        int4 t = c4[i];
        vals[4 * i + 0] = t.x; vals[4 * i + 1] = t.y;
        vals[4 * i + 2] = t.z; vals[4 * i + 3] = t.w;
        tot += (t.x + t.y) + (t.z + t.w);
    }
    // inclusive wave scan of thread totals
    int inc = tot;
    for (int o = 1; o < 64; o <<= 1) {
        int t = __shfl_up(inc, o);
        if (lane >= o) inc += t;
    }
    __shared__ int wsum[16], woff[16];
    if (lane == 63) wsum[wv] = inc;
    __syncthreads();
    if (tid == 0) {
        int r = 0;
        for (int w = 0; w < 16; ++w) { woff[w] = r; r += wsum[w]; }
    }
    __syncthreads();
    int run = woff[wv] + inc - tot;   // exclusive offset of this thread's chunk
    unsigned short* srow = start + (size_t)b * R3 + base;
    int* urow = cursor + (size_t)b * R3 + base;
    for (int i = 0; i < 32; ++i) {
        srow[i] = (unsigned short)run;
        urow[i] = run;
        run += vals[i];
    }
}

// ---------------------------------------------------------------------------
// K4: scatter point ids into voxel-sorted plist (u16). grid (N/256, B).
// ---------------------------------------------------------------------------
__global__ void plist_kernel(const unsigned short* __restrict__ idx,
                             int* __restrict__ cursor,
                             unsigned short* __restrict__ plist, int N) {
    const int n = blockIdx.x * blockDim.x + threadIdx.x;
    const int b = blockIdx.y;
    if (n >= N) return;
    const int v = idx[(size_t)b * N + n];
    const int pos = atomicAdd(&cursor[(size_t)b * R3 + v], 1);
    plist[(size_t)b * N + pos] = (unsigned short)n;
}

// ---------------------------------------------------------------------------
// K5: gather-sum. grid (D/2, B), block 1024, no LDS, no atomics.
// Thread-per-voxel (32 voxels each, stride 1024 -> per-lane load balance
// averages over x-slabs). Registers accumulate 2 dims per block; plist run
// is contiguous per voxel; feature gathers hit the L2-resident 128 KB row.
// ---------------------------------------------------------------------------
__global__ __launch_bounds__(1024) void reduce_kernel(
        const float* __restrict__ feats,
        const unsigned short* __restrict__ plist,
        const unsigned short* __restrict__ start,
        const int* __restrict__ counts,
        float* __restrict__ vox, int D, int N) {
    const int d0 = blockIdx.x * 2;
    const int b = blockIdx.y;
    const float* frow0 = feats + ((size_t)b * D + d0) * N;
    const float* frow1 = frow0 + N;
    const unsigned short* prow = plist + (size_t)b * N;
    const unsigned short* srow = start + (size_t)b * R3;
    const int* crow = counts + (size_t)b * R3;
    float* vrow0 = vox + ((size_t)b * D + d0) * R3;
    float* vrow1 = vrow0 + R3;

    for (int v = threadIdx.x; v < R3; v += 1024) {
        const int c = crow[v];
        const int s = srow[v];
        float a0 = 0.f, a1 = 0.f;
        int j = 0;
        for (; j + 4 <= c; j += 4) {
            const int p0 = prow[s + j + 0];
            const int p1 = prow[s + j + 1];
            const int p2 = prow[s + j + 2];
            const int p3 = prow[s + j + 3];
            a0 += (frow0[p0] + frow0[p1]) + (frow0[p2] + frow0[p3]);
            a1 += (frow1[p0] + frow1[p1]) + (frow1[p2] + frow1[p3]);
        }
        for (; j < c; ++j) {
            const int p = prow[s + j];
            a0 += frow0[p];
            a1 += frow1[p];
        }
        const float dn = (float)(c > 1 ? c : 1);
        vrow0[v] = a0 / dn;
        vrow1[v] = a1 / dn;
    }
}

extern "C" void kernel_launch(void* const* d_in, const int* in_sizes, int n_in,
                              void* d_out, int out_size, void* d_ws, size_t ws_size,
                              hipStream_t stream) {
    const float* feats  = (const float*)d_in[0];   // (B, D, N)
    const float* coords = (const float*)d_in[1];   // (B, 3, N)
    float* out = (float*)d_out;

    const int D = (int)(3LL * in_sizes[0] / in_sizes[1]);
    const int B = (int)((long long)(out_size - in_sizes[1]) / ((long long)D * R3));
    const int N = in_sizes[1] / (3 * B);

    float* vox_out = out;                          // (B, D, R3)
    float* nc_out  = out + (size_t)B * D * R3;     // (B, 3, N)

    // ws layout (byte offsets):
    //   0      accum   (B*4 f32)
    //   1024   maxsq   (B u32)
    //   4096   counts  (B*R3 i32)          <- memset 0
    //   +4BR3  cursor  (B*R3 i32)          <- written by scan
    //   +8BR3  start   (B*R3 u16)          <- written by scan
    //   +10BR3 idx     (B*N u16)           <- written by point
    //   +...   plist   (B*N u16)           <- written by plist_kernel
    const size_t BR3 = (size_t)B * R3;
    const size_t BN  = (size_t)B * N;
    float*          accum  = (float*)d_ws;
    unsigned*       maxsq  = (unsigned*)((char*)d_ws + 1024);
    int*            counts = (int*)((char*)d_ws + 4096);
    int*            cursor = (int*)((char*)d_ws + 4096 + 4 * BR3);
    unsigned short* start  = (unsigned short*)((char*)d_ws + 4096 + 8 * BR3);
    unsigned short* idx    = (unsigned short*)((char*)d_ws + 4096 + 10 * BR3);
    unsigned short* plist  = (unsigned short*)((char*)d_ws + 4096 + 10 * BR3 + 2 * BN);

    hipMemsetAsync(d_ws, 0, 4096 + 4 * BR3, stream);   // accum+maxsq+counts

    sums_kernel <<<dim3(16, B), dim3(256), 0, stream>>>(coords, accum, N);
    maxn_kernel <<<dim3(16, B), dim3(256), 0, stream>>>(coords, accum, maxsq, N);

    const int nvec = (N + 3) >> 2;
    point_kernel<<<dim3((nvec + 255) / 256, B), dim3(256), 0, stream>>>(
        coords, accum, maxsq, nc_out, idx, counts, N);

    scan_kernel <<<dim3(B), dim3(1024), 0, stream>>>(counts, cursor, start);

    plist_kernel<<<dim3((N + 255) / 256, B), dim3(256), 0, stream>>>(
        idx, cursor, plist, N);

    reduce_kernel<<<dim3(D / 2, B), dim3(1024), 0, stream>>>(
        feats, plist, start, counts, vox_out, D, N);
}

// Round 6
// 458.179 us; speedup vs baseline: 1.5462x; 1.5462x over previous
//
#include <hip/hip_runtime.h>

#define RES 32
#define R3 (RES * RES * RES)

// ---------------------------------------------------------------------------
// K1: per-batch stats, fused. grid (B), block 1024.
// Phase 0: zero counts row (removes memset dispatch).
// Phase 1: mean over N (float4). Phase 2: max ||c-mean||^2 (re-read, L2-hot).
// Writes mean[b*4+{0,1,2}] and denom[b] = 2*sqrt(max).
// ---------------------------------------------------------------------------
__global__ __launch_bounds__(1024) void stats_kernel(
        const float* __restrict__ coords,
        float* __restrict__ mean_out,
        float* __restrict__ denom_out,
        int* __restrict__ counts, int N) {
    const int b = blockIdx.x;
    const int tid = threadIdx.x;
    const float* cb = coords + (size_t)b * 3 * N;

    // phase 0: zero this batch's counts
    int4* cz = (int4*)(counts + (size_t)b * R3);
    const int4 zi = make_int4(0, 0, 0, 0);
    for (int i = tid; i < (R3 >> 2); i += 1024) cz[i] = zi;

    // phase 1: sums
    const int nvec = N >> 2;
    const float4* c0 = (const float4*)cb;
    const float4* c1 = (const float4*)(cb + N);
    const float4* c2 = (const float4*)(cb + 2 * N);
    float s0 = 0.f, s1 = 0.f, s2 = 0.f;
    for (int n = tid; n < nvec; n += 1024) {
        float4 a = c0[n]; s0 += (a.x + a.y) + (a.z + a.w);
        float4 c = c1[n]; s1 += (c.x + c.y) + (c.z + c.w);
        float4 d = c2[n]; s2 += (d.x + d.y) + (d.z + d.w);
    }
    if (tid == 0) {
        for (int n = nvec << 2; n < N; ++n) {
            s0 += cb[n]; s1 += cb[N + n]; s2 += cb[2 * N + n];
        }
    }
    for (int off = 32; off; off >>= 1) {
        s0 += __shfl_down(s0, off);
        s1 += __shfl_down(s1, off);
        s2 += __shfl_down(s2, off);
    }
    __shared__ float r0[16], r1[16], r2[16];
    __shared__ float mean_s[3];
    const int lane = tid & 63, wv = tid >> 6;
    if (lane == 0) { r0[wv] = s0; r1[wv] = s1; r2[wv] = s2; }
    __syncthreads();
    if (tid == 0) {
        float t0 = 0.f, t1 = 0.f, t2 = 0.f;
        for (int w = 0; w < 16; ++w) { t0 += r0[w]; t1 += r1[w]; t2 += r2[w]; }
        mean_s[0] = t0 / (float)N;
        mean_s[1] = t1 / (float)N;
        mean_s[2] = t2 / (float)N;
    }
    __syncthreads();
    const float m0 = mean_s[0], m1 = mean_s[1], m2 = mean_s[2];

    // phase 2: max squared centered norm
    float mx = 0.f;
    for (int n = tid; n < nvec; n += 1024) {
        float4 a = c0[n], c = c1[n], d = c2[n];
        a.x -= m0; a.y -= m0; a.z -= m0; a.w -= m0;
        c.x -= m1; c.y -= m1; c.z -= m1; c.w -= m1;
        d.x -= m2; d.y -= m2; d.z -= m2; d.w -= m2;
        mx = fmaxf(mx, a.x * a.x + c.x * c.x + d.x * d.x);
        mx = fmaxf(mx, a.y * a.y + c.y * c.y + d.y * d.y);
        mx = fmaxf(mx, a.z * a.z + c.z * c.z + d.z * d.z);
        mx = fmaxf(mx, a.w * a.w + c.w * c.w + d.w * d.w);
    }
    if (tid == 0) {
        for (int n = nvec << 2; n < N; ++n) {
            float a = cb[n] - m0, c = cb[N + n] - m1, d = cb[2 * N + n] - m2;
            mx = fmaxf(mx, a * a + c * c + d * d);
        }
    }
    for (int off = 32; off; off >>= 1) mx = fmaxf(mx, __shfl_down(mx, off));
    if (lane == 0) r0[wv] = mx;
    __syncthreads();
    if (tid == 0) {
        for (int w = 0; w < 16; ++w) mx = fmaxf(mx, r0[w]);
        mean_out[b * 4 + 0] = m0;
        mean_out[b * 4 + 1] = m1;
        mean_out[b * 4 + 2] = m2;
        denom_out[b] = 2.0f * sqrtf(mx);
    }
}

// ---------------------------------------------------------------------------
// K2: per-point normalize + voxel index (u16) + counts. 4 points/thread.
// True division to keep voxel indices bit-identical to ref.
// ---------------------------------------------------------------------------
__global__ void point_kernel(const float* __restrict__ coords,
                             const float* __restrict__ mean,
                             const float* __restrict__ denom_in,
                             float* __restrict__ nc_out,
                             unsigned short* __restrict__ idx_out,
                             int* __restrict__ counts, int N) {
    const int n4 = blockIdx.x * blockDim.x + threadIdx.x;
    const int b = blockIdx.y;
    const int nvec = (N + 3) >> 2;
    if (n4 >= nvec) return;

    const float* cb = coords + (size_t)b * 3 * N;
    const float m0 = mean[b * 4 + 0];
    const float m1 = mean[b * 4 + 1];
    const float m2 = mean[b * 4 + 2];
    const float denom = denom_in[b];
    float* ncb = nc_out + (size_t)b * 3 * N;
    unsigned short* irow = idx_out + (size_t)b * N;
    int* crow = counts + (size_t)b * R3;

    const int n0 = n4 << 2;
    if (n0 + 3 < N) {
        float4 a = *(const float4*)(cb + n0);
        float4 c = *(const float4*)(cb + N + n0);
        float4 d = *(const float4*)(cb + 2 * N + n0);
        float4 v0, v1, v2;
        int4 id;
        #define PROC(comp)                                                        \
        {                                                                         \
            float x = (a.comp - m0) / denom + 0.5f;                               \
            float y = (c.comp - m1) / denom + 0.5f;                               \
            float z = (d.comp - m2) / denom + 0.5f;                               \
            v0.comp = fminf(fmaxf(x * (float)RES, 0.f), (float)(RES - 1));        \
            v1.comp = fminf(fmaxf(y * (float)RES, 0.f), (float)(RES - 1));        \
            v2.comp = fminf(fmaxf(z * (float)RES, 0.f), (float)(RES - 1));        \
            id.comp = (int)rintf(v0.comp) * RES * RES                             \
                    + (int)rintf(v1.comp) * RES + (int)rintf(v2.comp);            \
        }
        PROC(x) PROC(y) PROC(z) PROC(w)
        #undef PROC
        *(float4*)(ncb + n0) = v0;
        *(float4*)(ncb + N + n0) = v1;
        *(float4*)(ncb + 2 * N + n0) = v2;
        ushort4 us;
        us.x = (unsigned short)id.x; us.y = (unsigned short)id.y;
        us.z = (unsigned short)id.z; us.w = (unsigned short)id.w;
        *(ushort4*)(irow + n0) = us;
        atomicAdd(&crow[id.x], 1);
        atomicAdd(&crow[id.y], 1);
        atomicAdd(&crow[id.z], 1);
        atomicAdd(&crow[id.w], 1);
    } else {
        for (int n = n0; n < N; ++n) {
            float x = (cb[n] - m0) / denom + 0.5f;
            float y = (cb[N + n] - m1) / denom + 0.5f;
            float z = (cb[2 * N + n] - m2) / denom + 0.5f;
            float v0 = fminf(fmaxf(x * (float)RES, 0.f), (float)(RES - 1));
            float v1 = fminf(fmaxf(y * (float)RES, 0.f), (float)(RES - 1));
            float v2 = fminf(fmaxf(z * (float)RES, 0.f), (float)(RES - 1));
            ncb[n] = v0; ncb[N + n] = v1; ncb[2 * N + n] = v2;
            int id = (int)rintf(v0) * RES * RES + (int)rintf(v1) * RES + (int)rintf(v2);
            irow[n] = (unsigned short)id;
            atomicAdd(&crow[id], 1);
        }
    }
}

// ---------------------------------------------------------------------------
// K3: fused scan + plist build. grid (B), block 1024.
// Exclusive scan of counts (32/thread in regs), start (u16) to global,
// running cursors privatized in LDS (128 KB), then plist scatter via
// native ds_add_rtn_u32 (int LDS atomics).
// ---------------------------------------------------------------------------
__global__ __launch_bounds__(1024) void scanplist_kernel(
        const int* __restrict__ counts,
        const unsigned short* __restrict__ idx,
        unsigned short* __restrict__ start,
        unsigned short* __restrict__ plist, int N) {
    const int b = blockIdx.x;
    const int tid = threadIdx.x;
    const int lane = tid & 63, wv = tid >> 6;
    const int base = tid * 32;
    const int* crow = counts + (size_t)b * R3;

    __shared__ int cursor[R3];   // 131072 bytes
    __shared__ int wsum[16], woff[16];

    int vals[32];
    int tot = 0;
    const int4* c4 = (const int4*)(crow + base);
    for (int i = 0; i < 8; ++i) {
        int4 t = c4[i];
        vals[4 * i + 0] = t.x; vals[4 * i + 1] = t.y;
        vals[4 * i + 2] = t.z; vals[4 * i + 3] = t.w;
        tot += (t.x + t.y) + (t.z + t.w);
    }
    int inc = tot;
    for (int o = 1; o < 64; o <<= 1) {
        int t = __shfl_up(inc, o);
        if (lane >= o) inc += t;
    }
    if (lane == 63) wsum[wv] = inc;
    __syncthreads();
    if (tid == 0) {
        int r = 0;
        for (int w = 0; w < 16; ++w) { woff[w] = r; r += wsum[w]; }
    }
    __syncthreads();
    int run = woff[wv] + inc - tot;   // exclusive offset of this thread's chunk
    unsigned short* srow = start + (size_t)b * R3 + base;
    for (int i = 0; i < 32; ++i) {
        srow[i] = (unsigned short)run;
        cursor[base + i] = run;
        run += vals[i];
    }
    __syncthreads();

    // plist scatter: pos = cursor[v]++ (LDS int atomic, native)
    const unsigned short* irow = idx + (size_t)b * N;
    unsigned short* prow = plist + (size_t)b * N;
    for (int n = tid; n < N; n += 1024) {
        const int v = irow[n];
        const int pos = atomicAdd(&cursor[v], 1);
        prow[pos] = (unsigned short)n;
    }
}

// ---------------------------------------------------------------------------
// K4: gather-sum from LDS-staged feature row. grid (D, B), block 1024.
// Stage frow (128 KB) into LDS coalesced; each thread owns 32 voxels,
// reads its contiguous plist run (sequential u16, unrolled x16 -> one
// vmcnt wait per 16 points), sums via ds_read. No atomics, no L2 thrash.
// ---------------------------------------------------------------------------
__global__ __launch_bounds__(1024) void reduce_kernel(
        const float* __restrict__ feats,
        const unsigned short* __restrict__ plist,
        const unsigned short* __restrict__ start,
        const int* __restrict__ counts,
        float* __restrict__ vox, int D, int N) {
    const int d = blockIdx.x;
    const int b = blockIdx.y;
    const int tid = threadIdx.x;

    __shared__ float row[R3];   // 131072 bytes
    const float* frow = feats + ((size_t)b * D + d) * N;
    {
        float4* r4 = (float4*)row;
        const float4* f4 = (const float4*)frow;
        for (int i = tid; i < (N >> 2); i += 1024) r4[i] = f4[i];
        if (tid == 0) for (int n = (N >> 2) << 2; n < N; ++n) row[n] = frow[n];
    }
    __syncthreads();

    const unsigned short* prow = plist + (size_t)b * N;
    const unsigned short* srow = start + (size_t)b * R3;
    const int* crow = counts + (size_t)b * R3;
    float* vrow = vox + ((size_t)b * D + d) * R3;

    for (int k = 0; k < R3 / 1024; ++k) {
        const int v = (k << 10) + tid;
        const int c = crow[v];
        const int s = srow[v];
        float a = 0.f;
        int j = 0;
        for (; j + 16 <= c; j += 16) {
            const unsigned short* pp = prow + s + j;
            const int p0 = pp[0],  p1 = pp[1],  p2 = pp[2],  p3 = pp[3];
            const int p4 = pp[4],  p5 = pp[5],  p6 = pp[6],  p7 = pp[7];
            const int p8 = pp[8],  p9 = pp[9],  pa = pp[10], pb = pp[11];
            const int pc = pp[12], pd = pp[13], pe = pp[14], pf = pp[15];
            float t0 = ((row[p0] + row[p1]) + (row[p2] + row[p3]))
                     + ((row[p4] + row[p5]) + (row[p6] + row[p7]));
            float t1 = ((row[p8] + row[p9]) + (row[pa] + row[pb]))
                     + ((row[pc] + row[pd]) + (row[pe] + row[pf]));
            a += t0 + t1;
        }
        for (; j + 4 <= c; j += 4) {
            const unsigned short* pp = prow + s + j;
            const int p0 = pp[0], p1 = pp[1], p2 = pp[2], p3 = pp[3];
            a += (row[p0] + row[p1]) + (row[p2] + row[p3]);
        }
        for (; j < c; ++j) a += row[prow[s + j]];
        vrow[v] = a / (float)(c > 1 ? c : 1);
    }
}

extern "C" void kernel_launch(void* const* d_in, const int* in_sizes, int n_in,
                              void* d_out, int out_size, void* d_ws, size_t ws_size,
                              hipStream_t stream) {
    const float* feats  = (const float*)d_in[0];   // (B, D, N)
    const float* coords = (const float*)d_in[1];   // (B, 3, N)
    float* out = (float*)d_out;

    const int D = (int)(3LL * in_sizes[0] / in_sizes[1]);
    const int B = (int)((long long)(out_size - in_sizes[1]) / ((long long)D * R3));
    const int N = in_sizes[1] / (3 * B);

    float* vox_out = out;                          // (B, D, R3)
    float* nc_out  = out + (size_t)B * D * R3;     // (B, 3, N)

    // ws layout (byte offsets), all regions fully overwritten every call:
    //   0              mean   (B*4 f32)   <- stats
    //   1024           denom  (B f32)     <- stats
    //   4096           counts (B*R3 i32)  <- zeroed by stats, filled by point
    //   4096+4BR3      start  (B*R3 u16)  <- scanplist
    //   4096+6BR3      idx    (B*N u16)   <- point
    //   4096+6BR3+2BN  plist  (B*N u16)   <- scanplist
    const size_t BR3 = (size_t)B * R3;
    const size_t BN  = (size_t)B * N;
    float*          mean   = (float*)d_ws;
    float*          denom  = (float*)((char*)d_ws + 1024);
    int*            counts = (int*)((char*)d_ws + 4096);
    unsigned short* start  = (unsigned short*)((char*)d_ws + 4096 + 4 * BR3);
    unsigned short* idx    = (unsigned short*)((char*)d_ws + 4096 + 6 * BR3);
    unsigned short* plist  = (unsigned short*)((char*)d_ws + 4096 + 6 * BR3 + 2 * BN);

    stats_kernel<<<dim3(B), dim3(1024), 0, stream>>>(coords, mean, denom, counts, N);

    const int nvec = (N + 3) >> 2;
    point_kernel<<<dim3((nvec + 255) / 256, B), dim3(256), 0, stream>>>(
        coords, mean, denom, nc_out, idx, counts, N);

    scanplist_kernel<<<dim3(B), dim3(1024), 0, stream>>>(counts, idx, start, plist, N);

    reduce_kernel<<<dim3(D, B), dim3(1024), 0, stream>>>(
        feats, plist, start, counts, vox_out, D, N);
}